// Round 3
// baseline (139.448 us; speedup 1.0000x reference)
//
#include <hip/hip_runtime.h>
#include <hip/hip_bf16.h>

// out[b,d,r] = sum_c p[b,c] * softmax_d( x[b,:] @ W[:, c*8+d, r] + bias[c,d,r] )
// B=16384, F=128, C=8, R=64.  bf16 MFMA 16x16x32, fully fused.
//
// R12->R13: R12 was latency-bound (MfmaUtil 13%, VALU 27%, Occ 28% -- all
// pipes idle): the per-c barrier+vmcnt(0) convoy serialized 16 barrier-
// synced waves/CU, the softmax shfl_xor added 8 ds_bpermute/c, and the
// [2d x 8r] store layout wrote 32B half-lines (WRITE_SIZE 64MB for a
// 33.5MB output).  B working set is tiny (32KB/wave/c, wf L2-resident),
// so LDS staging bought bandwidth we don't need at the price of all
// cross-wave overlap.  R13: ZERO LDS, ZERO barriers -- each wave loads
// its 32 B-fragments per c straight to registers (global_load_dwordx4,
// fragment layout in wf is already register-shaped; L1 catches the 4x
// intra-block reuse) and feeds MFMA directly.  All 16 waves/CU free-run;
// one wave's softmax overlaps another's loads.  Reverts to the proven
// R10 math layout: in-lane softmax over 8 d-accs (no shfl), 16-r column
// tiles -> 64B-coalesced stores, bias as MFMA C-in, w-major grid (all 4
// w-chunks of a row-group on one XCD for x/out L2 locality).
// acc 32 (AGPR) + O 32 + afr 16 + 8 in-flight B-frags 32 + addr ~ 120
// regs -> launch_bounds(256,4), grid 1024 = 4 blocks/CU all resident.

#define B_ROWS   16384
#define F_DIM    128
#define NCOL     4096      // C*C*R
#define OUT_STRIDE 512     // C*R
#define LOG2E    1.44269504088896340736f

typedef __bf16 bf16x8 __attribute__((ext_vector_type(8)));
typedef float  f32x4  __attribute__((ext_vector_type(4)));

// ---------------------------------------------------------------------------
// Prepass: W fp32 (128 x 4096 row-major) -> bf16 MFMA B-fragments.
// Tile t in [0,256) covers cols t*16..t*16+16; fragment (t,kk) holds
// k = kk*32 + (lane>>4)*8 + j, n = t*16 + (lane&15), at wf[(t*4+kk)*512].
// (identical to the proven R10 prepass)
// ---------------------------------------------------------------------------
__global__ void wconv_kernel(const float* __restrict__ W, __bf16* __restrict__ wf) {
    int f    = blockIdx.x * 256 + threadIdx.x;  // 0..65535
    int lane = f & 63;
    int tkk  = f >> 6;
    int t    = tkk >> 2;
    int kk   = tkk & 3;
    int kbase = kk * 32 + (lane >> 4) * 8;
    int n     = t * 16 + (lane & 15);
    bf16x8 frag;
#pragma unroll
    for (int j = 0; j < 8; ++j)
        frag[j] = (__bf16)W[(kbase + j) * NCOL + n];
    *(bf16x8*)(wf + (size_t)f * 8) = frag;
}

// ---------------------------------------------------------------------------
// Fused GEMM + bias + softmax(d) + p-contraction.  NO LDS, NO barriers.
// Block: 256 thr (4 waves), 64 batch rows, one 16-r chunk w = blockIdx>>8.
// Wave ww owns rows b0..b0+16.  Per c: 32 B-fragments (8 d x 4 kk) loaded
// per-wave straight to registers (8 in flight at a time); 8 accumulators
// (one per d) per lane; softmax over d is in-lane (8 exp2, 7-add tree,
// 1 rcp, 8 fma per jj).  C/D layout: col=lane&15 -> r, row=quad*4+jj -> b.
// ---------------------------------------------------------------------------
__global__ __launch_bounds__(256, 4)
void fused_kernel(const float* __restrict__ x, const float* __restrict__ p,
                  const float* __restrict__ bias, const __bf16* __restrict__ wf,
                  float* __restrict__ out) {
    const int lane = threadIdx.x & 63;
    const int ww   = threadIdx.x >> 6;   // wave 0..3 = m-tile
    const int quad = lane >> 4;
    const int l15  = lane & 15;
    const int w    = blockIdx.x >> 8;    // r-chunk 0..3 (w-major: XCD = g%8)
    const int g    = blockIdx.x & 255;   // row-group
    const int b0   = g * 64 + ww * 16;

    // A fragments: afr[kk][j] = x_bf16[b0+l15][kk*32 + quad*8 + j]
    bf16x8 afr[4];
    {
        const float* xr = x + (size_t)(b0 + l15) * F_DIM + quad * 8;
#pragma unroll
        for (int kk = 0; kk < 4; ++kk) {
            float4 lo = *(const float4*)(xr + kk * 32);
            float4 hi = *(const float4*)(xr + kk * 32 + 4);
            bf16x8 f;
            f[0] = (__bf16)lo.x; f[1] = (__bf16)lo.y;
            f[2] = (__bf16)lo.z; f[3] = (__bf16)lo.w;
            f[4] = (__bf16)hi.x; f[5] = (__bf16)hi.y;
            f[6] = (__bf16)hi.z; f[7] = (__bf16)hi.w;
            afr[kk] = f;
        }
    }

    float O[8][4] = {};   // [d][jj] output accumulator over c

#pragma unroll 1
    for (int c = 0; c < 8; ++c) {
        // p and bias issued first; latency hides under the B loads/MFMAs
        float pvv[4];
#pragma unroll
        for (int jj = 0; jj < 4; ++jj)
            pvv[jj] = p[(size_t)(b0 + quad * 4 + jj) * 8 + c];

        float bvl[8];
#pragma unroll
        for (int d = 0; d < 8; ++d)
            bvl[d] = bias[(c * 8 + d) * 64 + w * 16 + l15];

        // C-in = bias (row-invariant per column)
        f32x4 acc[8];
#pragma unroll
        for (int d = 0; d < 8; ++d) {
            f32x4 binit = {bvl[d], bvl[d], bvl[d], bvl[d]};
            acc[d] = binit;
        }

        // fragment gf = ((c*8+d)*4 + w)*4 + kk = c*128 + d*16 + w*4 + kk
        const __bf16* wc = wf + ((size_t)(c * 128 + w * 4)) * 512 + lane * 8;
#pragma unroll
        for (int kk = 0; kk < 4; ++kk) {
            bf16x8 bfr[8];
#pragma unroll
            for (int d = 0; d < 8; ++d)
                bfr[d] = *(const bf16x8*)(wc + (size_t)(d * 16 + kk) * 512);
#pragma unroll
            for (int d = 0; d < 8; ++d)
                acc[d] = __builtin_amdgcn_mfma_f32_16x16x32_bf16(
                             afr[kk], bfr[d], acc[d], 0, 0, 0);
        }

        // ---- in-lane softmax over d + p-weighted accumulate ---------------
#pragma unroll
        for (int jj = 0; jj < 4; ++jj) {
            float e[8];
#pragma unroll
            for (int d = 0; d < 8; ++d)
                e[d] = __builtin_amdgcn_exp2f(acc[d][jj] * LOG2E);
            float s01 = e[0] + e[1], s23 = e[2] + e[3];
            float s45 = e[4] + e[5], s67 = e[6] + e[7];
            float s = (s01 + s23) + (s45 + s67);
            float scale = pvv[jj] * __builtin_amdgcn_rcpf(s);
#pragma unroll
            for (int d = 0; d < 8; ++d)
                O[d][jj] = __builtin_fmaf(e[d], scale, O[d][jj]);
        }
    }

    // ---- stores: out[b, d*64 + w*16 + l15] — 64B per quad, full lines -----
#pragma unroll
    for (int jj = 0; jj < 4; ++jj) {
        float* orow = out + (size_t)(b0 + quad * 4 + jj) * OUT_STRIDE + w * 16 + l15;
#pragma unroll
        for (int d = 0; d < 8; ++d)
            orow[d * 64] = O[d][jj];
    }
}

extern "C" void kernel_launch(void* const* d_in, const int* in_sizes, int n_in,
                              void* d_out, int out_size, void* d_ws, size_t ws_size,
                              hipStream_t stream) {
    const float* x    = (const float*)d_in[0];   // (16384, 128)
    const float* p    = (const float*)d_in[1];   // (16384, 8)
    const float* W    = (const float*)d_in[2];   // (128, 64, 64)
    const float* bias = (const float*)d_in[3];   // (8, 8, 64)
    float* out = (float*)d_out;                  // (16384, 8, 64)
    __bf16* wf = (__bf16*)d_ws;                  // 1 MB bf16 fragments

    wconv_kernel<<<dim3(256), dim3(256), 0, stream>>>(W, wf);
    fused_kernel<<<dim3(1024), dim3(256), 0, stream>>>(x, p, bias, wf, out);
}

// Round 4
// 99.433 us; speedup vs baseline: 1.4024x; 1.4024x over previous
//
#include <hip/hip_runtime.h>
#include <hip/hip_bf16.h>

// out[b,d,r] = sum_c p[b,c] * softmax_d( x[b,:] @ W[:, c*8+d, r] + bias[c,d,r] )
// B=16384, F=128, C=8, R=64.  bf16 MFMA 16x16x32, fully fused.
//
// R13->R14: R13 proved (73us, HBM 10%, Mfma 9%) that B-fragments MUST be
// shared across waves via LDS: unshared register-direct loads pull 1GB
// through L2 at ~14TB/s effective.  R14 returns to the proven R10 baseline
// structure (M=16/wave, 8 in-lane d-accs, in-lane softmax w/ zero shuffles,
// full 64B-line stores, 32KB/c block-shared staging) and fixes ONLY its
// known defect -- the per-c exposed stage latency (R10: issue stage ->
// barrier's vmcnt(0) waits the just-issued loads -> compute, 8x):
//  - double-buffered 2x32KB stage; stage(c+1) issued right after the ONE
//    per-c barrier, so the next barrier's implicit vmcnt(0) finds it landed
//    (a full compute phase ~2-3kcyc covers the ~400cyc L2 latency).
//  - 512-thr / 8-wave blocks keep 16 waves/CU despite 64KB LDS/block:
//    grid 512 = 2 blocks/CU exact, launch_bounds(512,4) = 128-reg cap.
//  - w-major grid (w=blk>>7; 128%8==0 -> all 4 r-chunks of a row-group on
//    one XCD): x L2-filled once instead of 4x.
//  - bias folded into MFMA C-in.

#define B_ROWS   16384
#define F_DIM    128
#define NCOL     4096      // C*C*R
#define OUT_STRIDE 512     // C*R
#define LOG2E    1.44269504088896340736f

typedef __bf16 bf16x8 __attribute__((ext_vector_type(8)));
typedef float  f32x4  __attribute__((ext_vector_type(4)));

#define AS1(p) ((const __attribute__((address_space(1))) unsigned int*)(p))
#define AS3(p) ((__attribute__((address_space(3))) unsigned int*)(p))

// ---------------------------------------------------------------------------
// Prepass: W fp32 (128 x 4096 row-major) -> bf16 MFMA B-fragments.
// Tile t in [0,256) covers cols t*16..t*16+16; fragment (t,kk) holds
// k = kk*32 + (lane>>4)*8 + j, n = t*16 + (lane&15), at wf[(t*4+kk)*512].
// (identical to the proven R10 prepass)
// ---------------------------------------------------------------------------
__global__ void wconv_kernel(const float* __restrict__ W, __bf16* __restrict__ wf) {
    int f    = blockIdx.x * 256 + threadIdx.x;  // 0..65535
    int lane = f & 63;
    int tkk  = f >> 6;
    int t    = tkk >> 2;
    int kk   = tkk & 3;
    int kbase = kk * 32 + (lane >> 4) * 8;
    int n     = t * 16 + (lane & 15);
    bf16x8 frag;
#pragma unroll
    for (int j = 0; j < 8; ++j)
        frag[j] = (__bf16)W[(kbase + j) * NCOL + n];
    *(bf16x8*)(wf + (size_t)f * 8) = frag;
}

// ---------------------------------------------------------------------------
// Fused GEMM + bias + softmax(d) + p-contraction.
// Block: 512 thr (8 waves), 128 batch rows, one 16-r chunk w = blockIdx>>7.
// Wave ww owns rows b0..b0+16.  Per c: 32 fragments (8 d x 4 kk, 32 KB)
// double-buffer-staged (wave ww stages d=ww's 4 kk frags); each wave reads
// all 32 (block-shared).  8 accumulators (one per d) per lane; softmax over
// d is in-lane (8 exp2, 7-add tree, 1 rcp, 8 fma per jj); C-in = bias.
// C/D layout: col=lane&15 -> r, row=quad*4+jj -> batch row.
// ---------------------------------------------------------------------------
__global__ __launch_bounds__(512, 4)
void fused_kernel(const float* __restrict__ x, const float* __restrict__ p,
                  const float* __restrict__ bias, const __bf16* __restrict__ wf,
                  float* __restrict__ out) {
    __shared__ __align__(16) char lds[65536];   // 2 x (32 fragments = 32 KB)

    const int lane = threadIdx.x & 63;
    const int ww   = threadIdx.x >> 6;   // wave 0..7 = m-tile, also staged d
    const int quad = lane >> 4;
    const int l15  = lane & 15;
    const int w    = blockIdx.x >> 7;    // r-chunk 0..3 (w-major: XCD = g%8)
    const int g    = blockIdx.x & 127;   // row-group
    const int b0   = g * 128 + ww * 16;

    // ---- prologue: stage c=0 into buffer 0 (wave ww stages d=ww) ----------
    {
        const __bf16* src = wf + (size_t)(((0 * 8 + ww) * 4 + w) * 4) * 512 + lane * 8;
#pragma unroll
        for (int kk = 0; kk < 4; ++kk)
            __builtin_amdgcn_global_load_lds(
                AS1(src + kk * 512),
                AS3(lds + (ww * 4 + kk) * 1024), 16, 0, 0);
    }

    // A fragments: afr[kk][j] = x_bf16[b0+l15][kk*32 + quad*8 + j]
    bf16x8 afr[4];
    {
        const float* xr = x + (size_t)(b0 + l15) * F_DIM + quad * 8;
#pragma unroll
        for (int kk = 0; kk < 4; ++kk) {
            float4 lo = *(const float4*)(xr + kk * 32);
            float4 hi = *(const float4*)(xr + kk * 32 + 4);
            bf16x8 f;
            f[0] = (__bf16)lo.x; f[1] = (__bf16)lo.y;
            f[2] = (__bf16)lo.z; f[3] = (__bf16)lo.w;
            f[4] = (__bf16)hi.x; f[5] = (__bf16)hi.y;
            f[6] = (__bf16)hi.z; f[7] = (__bf16)hi.w;
            afr[kk] = f;
        }
    }

    float O[8][4] = {};   // [d][jj] output accumulator over c

#pragma unroll 1
    for (int c = 0; c < 8; ++c) {
        // barrier: stage(c) landed (its loads had the whole previous compute
        // phase in flight) AND all waves done reading buf[(c+1)&1].
        __syncthreads();

        // ---- issue stage(c+1) into the other buffer (hides under compute)
        if (c < 7) {
            const __bf16* src =
                wf + (size_t)((((c + 1) * 8 + ww) * 4 + w) * 4) * 512 + lane * 8;
            char* dst = lds + ((c + 1) & 1) * 32768;
#pragma unroll
            for (int kk = 0; kk < 4; ++kk)
                __builtin_amdgcn_global_load_lds(
                    AS1(src + kk * 512),
                    AS3(dst + (ww * 4 + kk) * 1024), 16, 0, 0);
        }

        // ---- p and bias loads issued before MFMAs (latency hides under them)
        float pvv[4];
#pragma unroll
        for (int jj = 0; jj < 4; ++jj)
            pvv[jj] = p[(size_t)(b0 + quad * 4 + jj) * 8 + c];

        float bvl[8];
#pragma unroll
        for (int d = 0; d < 8; ++d)
            bvl[d] = bias[(c * 8 + d) * 64 + w * 16 + l15];

        // C-in = bias (row-invariant per column)
        f32x4 acc[8];
#pragma unroll
        for (int d = 0; d < 8; ++d) {
            f32x4 binit = {bvl[d], bvl[d], bvl[d], bvl[d]};
            acc[d] = binit;
        }

        const char* buf = lds + (c & 1) * 32768;
#pragma unroll
        for (int kk = 0; kk < 4; ++kk) {
            bf16x8 bfr[8];
#pragma unroll
            for (int d = 0; d < 8; ++d)
                bfr[d] = *(const bf16x8*)(buf + (d * 4 + kk) * 1024 + lane * 16);
#pragma unroll
            for (int d = 0; d < 8; ++d)
                acc[d] = __builtin_amdgcn_mfma_f32_16x16x32_bf16(
                             afr[kk], bfr[d], acc[d], 0, 0, 0);
        }

        // ---- in-lane softmax over d + p-weighted accumulate ---------------
#pragma unroll
        for (int jj = 0; jj < 4; ++jj) {
            float e[8];
#pragma unroll
            for (int d = 0; d < 8; ++d)
                e[d] = __builtin_amdgcn_exp2f(acc[d][jj] * LOG2E);
            float s01 = e[0] + e[1], s23 = e[2] + e[3];
            float s45 = e[4] + e[5], s67 = e[6] + e[7];
            float s = (s01 + s23) + (s45 + s67);
            float scale = pvv[jj] * __builtin_amdgcn_rcpf(s);
#pragma unroll
            for (int d = 0; d < 8; ++d)
                O[d][jj] = __builtin_fmaf(e[d], scale, O[d][jj]);
        }
        // no second barrier: next iteration's __syncthreads covers the
        // write-after-read hazard on buf[(c+1)&1].
    }

    // ---- stores: out[b, d*64 + w*16 + l15] — 64B per quad, full lines -----
#pragma unroll
    for (int jj = 0; jj < 4; ++jj) {
        float* orow = out + (size_t)(b0 + quad * 4 + jj) * OUT_STRIDE + w * 16 + l15;
#pragma unroll
        for (int d = 0; d < 8; ++d)
            orow[d * 64] = O[d][jj];
    }
}

extern "C" void kernel_launch(void* const* d_in, const int* in_sizes, int n_in,
                              void* d_out, int out_size, void* d_ws, size_t ws_size,
                              hipStream_t stream) {
    const float* x    = (const float*)d_in[0];   // (16384, 128)
    const float* p    = (const float*)d_in[1];   // (16384, 8)
    const float* W    = (const float*)d_in[2];   // (128, 64, 64)
    const float* bias = (const float*)d_in[3];   // (8, 8, 64)
    float* out = (float*)d_out;                  // (16384, 8, 64)
    __bf16* wf = (__bf16*)d_ws;                  // 1 MB bf16 fragments

    wconv_kernel<<<dim3(256), dim3(256), 0, stream>>>(W, wf);
    fused_kernel<<<dim3(512), dim3(512), 0, stream>>>(x, p, bias, wf, out);
}